// Round 9
// baseline (1935.870 us; speedup 1.0000x reference)
//
#include <hip/hip_runtime.h>

// EnhancedQuantumInspiredLSTM on MI355X (gfx950).
// Round-9 = round-8 skeleton + three latency cuts:
//  (a) h0 per-step unique buffers (513 slots/domain) -> NO h0 WAR -> l0 polls
//      only its own 16 f0 flags; l1's heavier step can never throttle l0.
//  (b) split MFMA accumulator (2 chains of 16) -> half the dependent latency.
//  (c) tighter polls: no s_sleep, 64 lanes cover the 16 flag lines.
// Slot map: h0 slot s holds h0(s-1); slot 0 zeroed (= h(-1)).
//   l0 step t: stage slot t, publish slot t+1, flag f0=t+1.
//   l1 step t: stage h0 slot t+1 (poll f0>=t+1) + h1 slot (t-1)&1 (poll f1>=t),
//              publish h1 slot t&1, flag f1=t+1.

typedef _Float16 f16;
typedef _Float16 f16x8 __attribute__((ext_vector_type(8)));
typedef float f32x4 __attribute__((ext_vector_type(4)));
typedef unsigned long long u64;

#define MFMA16(a, b, c) __builtin_amdgcn_mfma_f32_16x16x32_f16((a), (b), (c), 0, 0, 0)
#define LD_AG(p) __hip_atomic_load((p), __ATOMIC_RELAXED, __HIP_MEMORY_SCOPE_AGENT)
#define ST_AG(p, v) __hip_atomic_store((p), (v), __ATOMIC_RELAXED, __HIP_MEMORY_SCOPE_AGENT)

// ---- workspace layout (bytes) ----
#define OFF_Q16 0UL           // 32768*512*2 = 33,554,432  rows = s*64+b
#define OFF_X16 33554432UL    // 8,388,608
#define OFF_W16 41943040UL    // 2*2048*1024*2 = 8,388,608  [l][row][k']
#define OFF_COS 50331648UL    // 131,072 (transposed [h][i])
#define OFF_SIN 50462720UL    // 131,072
#define OFF_BSUM 50593792UL   // 16,384
#define OFF_H1 50610176UL     // 4dom*2slot*16*512*2 = 131,072
#define OFF_HLAST 50741248UL  // 131,072
#define OFF_FC1WT 50872320UL  // 1,048,576
#define OFF_FLG 51920896UL    // 128 flags * 256B = 32,768
#define OFF_H0 51953664UL     // 4dom*513slot*16*512*2 = 33,619,968
#define WS_NEEDED 85573632UL  // <= 85,622,784 proven available (r4 ran)

// =====================================================================
// prep
// =====================================================================
__global__ __launch_bounds__(256) void k_prep(
    const float* __restrict__ x, const float* __restrict__ theta,
    const float* __restrict__ phi, const float* __restrict__ thn,
    const float* __restrict__ phn, const float* __restrict__ Wih,
    const float* __restrict__ Whh, const float* __restrict__ bih,
    const float* __restrict__ bhh, const float* __restrict__ fc1w,
    f16* __restrict__ x16, f16* __restrict__ w16, f16* __restrict__ cosT,
    f16* __restrict__ sinT, float* __restrict__ bsum, float* __restrict__ fc1wT,
    f16* __restrict__ h0buf, f16* __restrict__ h1buf, unsigned* __restrict__ flg) {
  const int T1 = 4194304;        // x16
  const int T2 = T1 + 4194304;   // w16 combined [l][2048][1024]
  const int T3 = T2 + 65536;     // cos/sin
  const int T4 = T3 + 262144;    // fc1wT
  const int T5 = T4 + 4096;      // bsum
  const int T6 = T5 + 98304;     // zero h1 (65536 f16) + h0 slot0 (4*8192 f16)
  const int T7 = T6 + 8192;      // zero flags (dwords)
  for (int idx = blockIdx.x * 256 + threadIdx.x; idx < T7; idx += gridDim.x * 256) {
    if (idx < T1) {
      int s = idx >> 13, rem = idx & 8191, b = rem >> 7, i = rem & 127;
      x16[idx] = (f16)x[b * 65536 + s * 128 + i];
    } else if (idx < T2) {
      int j = idx - T1;
      int l = j >> 21, rem = j & 2097151, r = rem >> 10, k = rem & 1023;
      float v = (k < 512) ? Wih[((size_t)l * 2048 + r) * 512 + k]
                          : Whh[((size_t)l * 2048 + r) * 512 + (k - 512)];
      w16[(size_t)l * 2097152 + (size_t)r * 1024 + k] = (f16)v;
    } else if (idx < T3) {
      int e = idx - T2;
      int i = e >> 9, h = e & 511;
      cosT[h * 128 + i] = (f16)cosf(theta[e] + thn[e]);
      sinT[h * 128 + i] = (f16)sinf(phi[e] + phn[e]);
    } else if (idx < T4) {
      int e = idx - T3;
      int n = e >> 9, k = e & 511;
      fc1wT[k * 512 + n] = fc1w[e];
    } else if (idx < T5) {
      int e = idx - T4;
      bsum[e] = bih[e] + bhh[e];
    } else if (idx < T6) {
      int e = idx - T5;
      if (e < 65536) {
        h1buf[e] = (f16)0.f;
      } else {
        int e2 = e - 65536;              // 4 dom x 8192: slot 0 of each domain
        int dm = e2 >> 13, o = e2 & 8191;
        h0buf[(size_t)dm * 513 * 8192 + o] = (f16)0.f;
      }
    } else {
      flg[idx - T6] = 0u;
    }
  }
}

// =====================================================================
// quantum: q16[(s*64+b)][h] = |x.(cos+isin)|, fp16 MFMA (unchanged)
// =====================================================================
__global__ __launch_bounds__(256) void k_quantum(
    const f16* __restrict__ x16, const f16* __restrict__ cosT,
    const f16* __restrict__ sinT, f16* __restrict__ q16) {
  __shared__ __align__(16) f16 a_lds[64 * 136];
  const int tid = threadIdx.x;
  const int r0 = blockIdx.x * 64, h0 = blockIdx.y * 128;
#pragma unroll
  for (int g = 0; g < 4; ++g) {
    int G = g * 256 + tid, row = G >> 4, col = G & 15;
    *(uint4*)((char*)a_lds + row * 272 + col * 16) =
        *(const uint4*)(x16 + (size_t)(r0 + row) * 128 + col * 8);
  }
  __syncthreads();
  const int wv = tid >> 6, lane = tid & 63, n15 = lane & 15, quad = lane >> 4;
  const int nb = h0 + wv * 32;
  f32x4 ac[4][2], as_[4][2];
#pragma unroll
  for (int mt = 0; mt < 4; ++mt)
#pragma unroll
    for (int nt = 0; nt < 2; ++nt) {
      ac[mt][nt] = (f32x4){0.f, 0.f, 0.f, 0.f};
      as_[mt][nt] = (f32x4){0.f, 0.f, 0.f, 0.f};
    }
#pragma unroll
  for (int it = 0; it < 4; ++it) {
    f16x8 a[4];
#pragma unroll
    for (int mt = 0; mt < 4; ++mt)
      a[mt] = *(const f16x8*)((const char*)a_lds + (mt * 16 + n15) * 272 + it * 64 + quad * 16);
#pragma unroll
    for (int nt = 0; nt < 2; ++nt) {
      const f16x8 bc = *(const f16x8*)(cosT + (size_t)(nb + nt * 16 + n15) * 128 + it * 32 + quad * 8);
      const f16x8 bs = *(const f16x8*)(sinT + (size_t)(nb + nt * 16 + n15) * 128 + it * 32 + quad * 8);
#pragma unroll
      for (int mt = 0; mt < 4; ++mt) {
        ac[mt][nt] = MFMA16(a[mt], bc, ac[mt][nt]);
        as_[mt][nt] = MFMA16(a[mt], bs, as_[mt][nt]);
      }
    }
  }
#pragma unroll
  for (int mt = 0; mt < 4; ++mt)
#pragma unroll
    for (int nt = 0; nt < 2; ++nt)
#pragma unroll
      for (int r = 0; r < 4; ++r) {
        int row = r0 + mt * 16 + quad * 4 + r;
        int col = nb + nt * 16 + n15;
        float re = ac[mt][nt][r], im = as_[mt][nt][r];
        q16[(size_t)row * 512 + col] = (f16)sqrtf(re * re + im * im);
      }
}

// =====================================================================
// k_rec helpers
// =====================================================================
__device__ __forceinline__ f16x8 lds_a(const char* astage, int row, int it, int quad) {
  int pos = (it * 4 + quad) ^ (row & 7);  // XOR swizzle on low-3 granule bits
  return *(const f16x8*)(astage + row * 2048 + pos * 16);
}
__device__ __forceinline__ float sigf(float x) { return 1.f / (1.f + __expf(-x)); }
__device__ __forceinline__ float tanhf_fast(float x) { return 1.f - 2.f / (__expf(2.f * x) + 1.f); }

// =====================================================================
// k_rec: 128 WGs x 512 thr. dom=blockIdx>>5 (16 batch rows), role=blockIdx&31:
// roles 0-15 layer0 (32 h-cols each), 16-31 layer1.
// =====================================================================
__global__ __launch_bounds__(512, 2) void k_rec(
    const f16* __restrict__ q16, const f16* __restrict__ w16,
    const float* __restrict__ bsum, f16* __restrict__ h0buf,
    f16* __restrict__ h1buf, float* __restrict__ hlast, unsigned* flg) {
  __shared__ __align__(16) char astage[32768];  // 16 rows x 1024 f16
  __shared__ float gbuf[16 * 132];

  const int tid = threadIdx.x, lane = tid & 63, wv = tid >> 6;
  const int n15 = lane & 15, quad = lane >> 4;
  const int qg = wv >> 1, ch = wv & 1;  // gate, col-half for this wave
  const int dom = blockIdx.x >> 5, role = blockIdx.x & 31;
  const int l = role >> 4, c0 = (role & 15) * 32;
  const int b0 = dom * 16;

  // resident combined weights: rows qg*512 + c0 + ch*16 + n15, K'=1024
  f16x8 wf[32];
  {
    const f16* wbase = w16 + ((size_t)l * 2048 + (size_t)(qg * 512 + c0 + ch * 16 + n15)) * 1024 + quad * 8;
#pragma unroll
    for (int it = 0; it < 32; ++it) wf[it] = *(const f16x8*)(wbase + it * 32);
  }
  float bb[4][2];  // used by ew threads (tid<256): b=tid>>4, jc=(tid&15)*2
#pragma unroll
  for (int g = 0; g < 4; ++g)
#pragma unroll
    for (int j = 0; j < 2; ++j)
      bb[g][j] = bsum[l * 2048 + g * 512 + c0 + (tid & 15) * 2 + j];
  float cs0 = 0.f, cs1 = 0.f;

  // flags: [dom][layer][16 producers], 256B (64-dword) stride
  unsigned* f0 = flg + (size_t)(dom * 2 + 0) * 1024;
  unsigned* f1 = flg + (size_t)(dom * 2 + 1) * 1024;
  unsigned* myflag = (l ? f1 : f0) + (size_t)(role & 15) * 64;
  // l0: all 64 lanes cover the 16 f0 lines (4x redundant).
  // l1: lanes 0-31 -> f0 (target t+1), lanes 32-63 -> f1 (target t).
  const unsigned* pollp;
  if (l == 0) pollp = f0 + (size_t)(lane & 15) * 64;
  else pollp = (lane < 32) ? (f0 + (size_t)(lane & 15) * 64)
                           : (f1 + (size_t)(lane & 15) * 64);

  // staging: thread -> row=tid>>5 (16), colgrp=tid&31 (32 x 16 f16 = 32B)
  const int srow = tid >> 5, scg = tid & 31;
  const int g0 = scg * 2;
  char* a_x0 = astage + srow * 2048 + ((g0 ^ (srow & 7)) * 16);
  char* a_x1 = astage + srow * 2048 + (((g0 + 1) ^ (srow & 7)) * 16);
  char* a_h0 = a_x0 + 1024;  // granule +64 (low-3 XOR unaffected)
  char* a_h1 = a_x1 + 1024;
  const size_t soff = (size_t)srow * 512 + scg * 16;  // within a 16x512 slot
  const size_t h0base = (size_t)dom * 513 * 8192;     // per-step unique slots
  const size_t h1base = (size_t)dom * 2 * 8192;

  for (int t = 0; t <= 511; ++t) {
    // stage x-part for l0 (immutable q, plain cached loads)
    if (l == 0) {
      const f16* src = q16 + ((size_t)(t * 64 + b0 + srow)) * 512 + scg * 16;
      uint4 v0 = *(const uint4*)src;
      uint4 v1 = *(const uint4*)(src + 8);
      *(uint4*)a_x0 = v0;
      *(uint4*)a_x1 = v1;
    }
    // poll: l0 needs f0>=t (peers done t-1; h0 slot t complete).
    //       l1 needs f0>=t+1 (h0(t) slot t+1) and f1>=t (peers' h1(t-1)).
    if (l == 0) {
      if (t >= 1) {
        while (true) {
          int f = (int)LD_AG(pollp);
          if (__all(f >= t)) break;
        }
      }
    } else {
      const int mytgt = (lane < 32) ? (t + 1) : t;
      while (true) {
        int f = (int)LD_AG(pollp);
        if (__all(f >= mytgt)) break;
      }
    }
    // stage h-part(s) (AGENT coherent loads)
    if (l == 0) {
      const u64* hs0 = (const u64*)(h0buf + h0base + (size_t)t * 8192 + soff);
      u64 x0 = LD_AG(hs0);
      u64 x1 = LD_AG(hs0 + 1);
      u64 x2 = LD_AG(hs0 + 2);
      u64 x3 = LD_AG(hs0 + 3);
      ((u64*)a_h0)[0] = x0; ((u64*)a_h0)[1] = x1;
      ((u64*)a_h1)[0] = x2; ((u64*)a_h1)[1] = x3;
    } else {
      const u64* hs0 = (const u64*)(h0buf + h0base + (size_t)(t + 1) * 8192 + soff);  // h0(t)
      u64 x0 = LD_AG(hs0);
      u64 x1 = LD_AG(hs0 + 1);
      u64 x2 = LD_AG(hs0 + 2);
      u64 x3 = LD_AG(hs0 + 3);
      const u64* hs1 = (const u64*)(h1buf + h1base + (size_t)((t - 1) & 1) * 8192 + soff);  // h1(t-1)
      u64 y0 = LD_AG(hs1);
      u64 y1 = LD_AG(hs1 + 1);
      u64 y2 = LD_AG(hs1 + 2);
      u64 y3 = LD_AG(hs1 + 3);
      ((u64*)a_x0)[0] = x0; ((u64*)a_x0)[1] = x1;
      ((u64*)a_x1)[0] = x2; ((u64*)a_x1)[1] = x3;
      ((u64*)a_h0)[0] = y0; ((u64*)a_h0)[1] = y1;
      ((u64*)a_h1)[0] = y2; ((u64*)a_h1)[1] = y3;
    }
    __syncthreads();  // B1: A-tile ready

    // fused GEMM K'=1024, split accumulator (2 dependent chains of 16)
    f32x4 acca = (f32x4){0.f, 0.f, 0.f, 0.f};
    f32x4 accb = (f32x4){0.f, 0.f, 0.f, 0.f};
#pragma unroll
    for (int it = 0; it < 16; ++it) {
      acca = MFMA16(lds_a(astage, n15, 2 * it, quad), wf[2 * it], acca);
      accb = MFMA16(lds_a(astage, n15, 2 * it + 1, quad), wf[2 * it + 1], accb);
    }
#pragma unroll
    for (int r = 0; r < 4; ++r)
      gbuf[(quad * 4 + r) * 132 + qg * 33 + ch * 16 + n15] = acca[r] + accb[r];
    __syncthreads();  // B2: gbuf ready (astage reads done)

    // elementwise + publish (threads 0-255: b=tid>>4, 2 cols)
    if (tid < 256) {
      const int b = tid >> 4, jc = (tid & 15) * 2;
      float hv[2];
#pragma unroll
      for (int j = 0; j < 2; ++j) {
        const float* gb = gbuf + b * 132 + jc + j;
        float gi = gb[0] + bb[0][j];
        float gf = gb[33] + bb[1][j];
        float gg = gb[66] + bb[2][j];
        float go = gb[99] + bb[3][j];
        float cprev = j ? cs1 : cs0;
        float c = sigf(gf) * cprev + sigf(gi) * tanhf_fast(gg);
        if (j) cs1 = c; else cs0 = c;
        hv[j] = sigf(go) * tanhf_fast(c);
      }
      union { f16 h2[2]; unsigned u; } pk;
      pk.h2[0] = (f16)hv[0];
      pk.h2[1] = (f16)hv[1];
      f16* dst = (l == 0)
          ? h0buf + h0base + (size_t)(t + 1) * 8192 + (size_t)b * 512 + c0 + jc
          : h1buf + h1base + (size_t)(t & 1) * 8192 + (size_t)b * 512 + c0 + jc;
      ST_AG((unsigned*)dst, pk.u);
      if (l == 1 && t == 511) {
        hlast[(size_t)(b0 + b) * 512 + c0 + jc] = hv[0];
        hlast[(size_t)(b0 + b) * 512 + c0 + jc + 1] = hv[1];
      }
    }
    __syncthreads();  // B3: vmcnt drained -> h stores visible
    if (tid == 0) ST_AG(myflag, (unsigned)(t + 1));
  }
}

// =====================================================================
// fc head
// =====================================================================
__global__ __launch_bounds__(512) void k_fc(
    const float* __restrict__ hlast, const float* __restrict__ fc1wT,
    const float* __restrict__ fc1b, const float* __restrict__ fc2w,
    const float* __restrict__ fc2b, float* __restrict__ out) {
  __shared__ float hrow[512];
  __shared__ float red[8];
  const int b = blockIdx.x, tid = threadIdx.x;
  hrow[tid] = hlast[b * 512 + tid];
  __syncthreads();
  float acc = 0.f;
#pragma unroll 8
  for (int k = 0; k < 512; ++k) acc += hrow[k] * fc1wT[k * 512 + tid];
  float h1 = acc + fc1b[tid];
  h1 = h1 > 0.f ? h1 : 0.f;
  float v = h1 * fc2w[tid];
#pragma unroll
  for (int off = 32; off >= 1; off >>= 1) v += __shfl_down(v, off);
  if ((tid & 63) == 0) red[tid >> 6] = v;
  __syncthreads();
  if (tid == 0) {
    float s = 0.f;
#pragma unroll
    for (int w = 0; w < 8; ++w) s += red[w];
    out[b] = s + fc2b[0];
  }
}

// =====================================================================
extern "C" void kernel_launch(void* const* d_in, const int* in_sizes, int n_in,
                              void* d_out, int out_size, void* d_ws, size_t ws_size,
                              hipStream_t stream) {
  if (ws_size < WS_NEEDED) return;  // fail loudly

  const float* x = (const float*)d_in[0];
  const float* theta = (const float*)d_in[1];
  const float* phi = (const float*)d_in[2];
  const float* thn = (const float*)d_in[3];
  const float* phn = (const float*)d_in[4];
  const float* Wih = (const float*)d_in[5];
  const float* Whh = (const float*)d_in[6];
  const float* bih = (const float*)d_in[7];
  const float* bhh = (const float*)d_in[8];
  const float* fc1w = (const float*)d_in[9];
  const float* fc1b = (const float*)d_in[10];
  const float* fc2w = (const float*)d_in[11];
  const float* fc2b = (const float*)d_in[12];

  char* ws = (char*)d_ws;
  f16* q16 = (f16*)(ws + OFF_Q16);
  f16* x16 = (f16*)(ws + OFF_X16);
  f16* w16 = (f16*)(ws + OFF_W16);
  f16* cosT = (f16*)(ws + OFF_COS);
  f16* sinT = (f16*)(ws + OFF_SIN);
  float* bsum = (float*)(ws + OFF_BSUM);
  f16* h1buf = (f16*)(ws + OFF_H1);
  f16* h0buf = (f16*)(ws + OFF_H0);
  float* hlast = (float*)(ws + OFF_HLAST);
  float* fc1wT = (float*)(ws + OFF_FC1WT);
  unsigned* flg = (unsigned*)(ws + OFF_FLG);

  k_prep<<<2048, 256, 0, stream>>>(x, theta, phi, thn, phn, Wih, Whh, bih, bhh, fc1w,
                                   x16, w16, cosT, sinT, bsum, fc1wT, h0buf, h1buf, flg);
  k_quantum<<<dim3(512, 4, 1), 256, 0, stream>>>(x16, cosT, sinT, q16);
  k_rec<<<128, 512, 0, stream>>>(q16, w16, bsum, h0buf, h1buf, hlast, flg);
  k_fc<<<64, 512, 0, stream>>>(hlast, fc1wT, fc1b, fc2w, fc2b, (float*)d_out);
}